// Round 1
// baseline (368.747 us; speedup 1.0000x reference)
//
#include <hip/hip_runtime.h>
#include <hip/hip_bf16.h>

#define B_SZ 8192
#define D_SZ 1024

typedef __attribute__((ext_vector_type(8))) short short8;
typedef __attribute__((ext_vector_type(4))) float floatx4;

// round-to-nearest-even f32 -> bf16 (values here are small/normal; no NaN path needed)
__device__ __forceinline__ unsigned short f2bf(float f) {
    union { float f; unsigned u; } v; v.f = f;
    unsigned r = v.u + 0x7FFF + ((v.u >> 16) & 1);
    return (unsigned short)(r >> 16);
}

__device__ __forceinline__ void glds16(const void* g, void* l) {
    __builtin_amdgcn_global_load_lds(
        (const __attribute__((address_space(1))) void*)g,
        (__attribute__((address_space(3))) void*)l, 16, 0, 0);
}

// One block per row (blocks 0..8191 = img, 8192..16383 = txt).
// 256 threads x float4 = 1024 elements. L2-normalize, cast to bf16.
__global__ __launch_bounds__(256) void norm_cast_kernel(
    const float* __restrict__ img, const float* __restrict__ txt,
    unsigned short* __restrict__ imgN, unsigned short* __restrict__ txtN)
{
    int b = blockIdx.x;
    const float* src; unsigned short* dst;
    if (b < B_SZ) { src = img + (size_t)b * D_SZ; dst = imgN + (size_t)b * D_SZ; }
    else { b -= B_SZ; src = txt + (size_t)b * D_SZ; dst = txtN + (size_t)b * D_SZ; }

    const int t = threadIdx.x;
    float4 v = ((const float4*)src)[t];
    float ss = v.x*v.x + v.y*v.y + v.z*v.z + v.w*v.w;
    #pragma unroll
    for (int off = 32; off > 0; off >>= 1) ss += __shfl_down(ss, off, 64);

    __shared__ float p[4];
    const int lane = t & 63, w = t >> 6;
    if (lane == 0) p[w] = ss;
    __syncthreads();
    float tot = p[0] + p[1] + p[2] + p[3];
    float scale = 1.0f / fmaxf(sqrtf(tot), 1e-12f);

    ushort4 o;
    o.x = f2bf(v.x * scale); o.y = f2bf(v.y * scale);
    o.z = f2bf(v.z * scale); o.w = f2bf(v.w * scale);
    ((ushort4*)dst)[t] = o;
}

// Fused bf16 GEMM (A @ B^T form: both K-contiguous) + SigLIP loss reduction.
// 128x128 tile / block, 256 threads = 4 waves in 2x2, each wave 64x64 via
// 4x4 grid of 16x16x32 MFMA. BK=32 (one MFMA consumes full K-step).
__global__ __launch_bounds__(256) void siglip_gemm_loss(
    const unsigned short* __restrict__ A,   // imgN [B,D] bf16 raw
    const unsigned short* __restrict__ Bt,  // txtN [B,D] bf16 raw
    const float* __restrict__ tp, const float* __restrict__ bp,
    float* __restrict__ out)
{
    __shared__ __align__(16) unsigned short As[128 * 32];
    __shared__ __align__(16) unsigned short Bs[128 * 32];

    const int tid  = threadIdx.x;
    const int lane = tid & 63;
    const int wave = tid >> 6;
    const int wm = wave & 1, wn = wave >> 1;
    const int bi = blockIdx.x * 128;
    const int bj = blockIdx.y * 128;
    const int quad = lane >> 4;   // 0..3
    const int l16  = lane & 15;

    floatx4 acc[4][4];
    #pragma unroll
    for (int i = 0; i < 4; ++i)
        #pragma unroll
        for (int j = 0; j < 4; ++j)
            acc[i][j] = (floatx4){0.f, 0.f, 0.f, 0.f};

    for (int k0 = 0; k0 < D_SZ; k0 += 32) {
        // stage 128x32 bf16 tiles of A and Bt: 512 x 16B granules each,
        // slot s -> row = s>>2, col-granule = s&3. LDS addr = s*16B is
        // wave-uniform-base + lane*16 as global_load_lds requires.
        #pragma unroll
        for (int it = 0; it < 2; ++it) {
            int s = tid + it * 256;
            int row = s >> 2, q = s & 3;
            glds16(A  + ((size_t)(bi + row) * D_SZ + k0 + q * 8), As + s * 8);
            glds16(Bt + ((size_t)(bj + row) * D_SZ + k0 + q * 8), Bs + s * 8);
        }
        __syncthreads();   // drains vmcnt (global_load_lds) before reads

        short8 af[4], bf[4];
        #pragma unroll
        for (int mt = 0; mt < 4; ++mt) {
            int r = wm * 64 + mt * 16 + l16;
            af[mt] = *(const short8*)(As + r * 32 + quad * 8);
        }
        #pragma unroll
        for (int nt = 0; nt < 4; ++nt) {
            int r = wn * 64 + nt * 16 + l16;
            bf[nt] = *(const short8*)(Bs + r * 32 + quad * 8);
        }
        #pragma unroll
        for (int mt = 0; mt < 4; ++mt)
            #pragma unroll
            for (int nt = 0; nt < 4; ++nt)
                acc[mt][nt] = __builtin_amdgcn_mfma_f32_16x16x32_bf16(
                    af[mt], bf[nt], acc[mt][nt], 0, 0, 0);
        __syncthreads();   // protect LDS before next stage overwrites
    }

    // Epilogue: logits -> -log_sigmoid(label*logit) = softplus(-z), reduce.
    const float t    = fminf(expf(tp[0]), 100.0f);
    const float bias = bp[0];
    float lsum = 0.0f;
    #pragma unroll
    for (int mt = 0; mt < 4; ++mt) {
        #pragma unroll
        for (int nt = 0; nt < 4; ++nt) {
            const int jj = bj + wn * 64 + nt * 16 + l16;           // C/D col = lane&15
            #pragma unroll
            for (int r = 0; r < 4; ++r) {
                const int ii = bi + wm * 64 + mt * 16 + quad * 4 + r; // C/D row
                float logit = fmaf(acc[mt][nt][r], t, bias);
                float z = (ii == jj) ? logit : -logit;
                // softplus(-z) = max(-z,0) + log1p(exp(-|z|))
                lsum += fmaxf(-z, 0.0f) + log1pf(expf(-fabsf(z)));
            }
        }
    }
    #pragma unroll
    for (int off = 32; off > 0; off >>= 1) lsum += __shfl_down(lsum, off, 64);

    __shared__ float red[4];
    if (lane == 0) red[wave] = lsum;
    __syncthreads();
    if (tid == 0)
        atomicAdd(out, (red[0] + red[1] + red[2] + red[3]) * (1.0f / (float)B_SZ));
}

extern "C" void kernel_launch(void* const* d_in, const int* in_sizes, int n_in,
                              void* d_out, int out_size, void* d_ws, size_t ws_size,
                              hipStream_t stream) {
    const float* img = (const float*)d_in[0];
    const float* txt = (const float*)d_in[1];
    const float* tp  = (const float*)d_in[2];
    const float* bp  = (const float*)d_in[3];
    float* out = (float*)d_out;

    unsigned short* imgN = (unsigned short*)d_ws;                 // 16 MB
    unsigned short* txtN = imgN + (size_t)B_SZ * D_SZ;            // 16 MB

    hipMemsetAsync(out, 0, sizeof(float), stream);                // graph-capturable
    norm_cast_kernel<<<2 * B_SZ, 256, 0, stream>>>(img, txt, imgN, txtN);
    dim3 grid(B_SZ / 128, B_SZ / 128);
    siglip_gemm_loss<<<grid, 256, 0, stream>>>(imgN, txtN, tp, bp, out);
}

// Round 2
// 277.535 us; speedup vs baseline: 1.3287x; 1.3287x over previous
//
#include <hip/hip_runtime.h>
#include <hip/hip_bf16.h>

#define B_SZ 8192
#define D_SZ 1024

typedef __attribute__((ext_vector_type(8))) short short8;
typedef __attribute__((ext_vector_type(4))) float floatx4;

// round-to-nearest-even f32 -> bf16 (values here are small/normal; no NaN path needed)
__device__ __forceinline__ unsigned short f2bf(float f) {
    union { float f; unsigned u; } v; v.f = f;
    unsigned r = v.u + 0x7FFF + ((v.u >> 16) & 1);
    return (unsigned short)(r >> 16);
}

__device__ __forceinline__ void glds16(const void* g, void* l) {
    __builtin_amdgcn_global_load_lds(
        (const __attribute__((address_space(1))) void*)g,
        (__attribute__((address_space(3))) void*)l, 16, 0, 0);
}

// One block per row (blocks 0..8191 = img, 8192..16383 = txt).
// 256 threads x float4 = 1024 elements. L2-normalize, cast to bf16.
__global__ __launch_bounds__(256) void norm_cast_kernel(
    const float* __restrict__ img, const float* __restrict__ txt,
    unsigned short* __restrict__ imgN, unsigned short* __restrict__ txtN)
{
    int b = blockIdx.x;
    const float* src; unsigned short* dst;
    if (b < B_SZ) { src = img + (size_t)b * D_SZ; dst = imgN + (size_t)b * D_SZ; }
    else { b -= B_SZ; src = txt + (size_t)b * D_SZ; dst = txtN + (size_t)b * D_SZ; }

    const int t = threadIdx.x;
    float4 v = ((const float4*)src)[t];
    float ss = v.x*v.x + v.y*v.y + v.z*v.z + v.w*v.w;
    #pragma unroll
    for (int off = 32; off > 0; off >>= 1) ss += __shfl_down(ss, off, 64);

    __shared__ float p[4];
    const int lane = t & 63, w = t >> 6;
    if (lane == 0) p[w] = ss;
    __syncthreads();
    float tot = p[0] + p[1] + p[2] + p[3];
    float scale = 1.0f / fmaxf(sqrtf(tot), 1e-12f);

    ushort4 o;
    o.x = f2bf(v.x * scale); o.y = f2bf(v.y * scale);
    o.z = f2bf(v.z * scale); o.w = f2bf(v.w * scale);
    ((ushort4*)dst)[t] = o;
}

// Fused bf16 GEMM (A @ B^T form: both K-contiguous) + SigLIP loss reduction.
// 128x128 tile / block, 256 threads = 4 waves in 2x2, each wave 64x64 via
// 4x4 grid of 16x16x32 MFMA. BK=32 (one MFMA consumes full K-step).
//
// LDS layout: row stride = 64 B (half a 128 B bank cycle). The 16 B granule
// at logical (row, q) is stored at physical position p = q ^ ((row>>1)&3).
// Swizzle is applied on the GLOBAL address side of global_load_lds (per-lane
// regs), keeping the LDS side contiguous in slot index as the DMA requires.
// Fragment ds_read_b128s then alias at most 2 lanes/bank-chunk (free, m136)
// instead of 8-way.
__global__ __launch_bounds__(256) void siglip_gemm_loss(
    const unsigned short* __restrict__ A,   // imgN [B,D] bf16 raw
    const unsigned short* __restrict__ Bt,  // txtN [B,D] bf16 raw
    const float* __restrict__ tp, const float* __restrict__ bp,
    float* __restrict__ out)
{
    __shared__ __align__(16) unsigned short As[128 * 32];
    __shared__ __align__(16) unsigned short Bs[128 * 32];

    const int tid  = threadIdx.x;
    const int lane = tid & 63;
    const int wave = tid >> 6;
    const int wm = wave & 1, wn = wave >> 1;
    const int bi = blockIdx.x * 128;
    const int bj = blockIdx.y * 128;
    const int quad = lane >> 4;   // 0..3
    const int l16  = lane & 15;

    floatx4 acc[4][4];
    #pragma unroll
    for (int i = 0; i < 4; ++i)
        #pragma unroll
        for (int j = 0; j < 4; ++j)
            acc[i][j] = (floatx4){0.f, 0.f, 0.f, 0.f};

    // physical granule position for fragment reads (row-dependent part of the
    // swizzle only depends on l16 since the row base is a multiple of 16)
    const int pfrag = quad ^ ((l16 >> 1) & 3);

    for (int k0 = 0; k0 < D_SZ; k0 += 32) {
        // stage 128x32 bf16 tiles of A and Bt: 512 x 16B granules each.
        // slot s -> row = s>>2, physical pos p = s&3, global granule
        // g = p ^ ((row>>1)&3). LDS dest = s*16 stays lane-contiguous.
        #pragma unroll
        for (int it = 0; it < 2; ++it) {
            int s = tid + it * 256;
            int row = s >> 2, p = s & 3;
            int g = p ^ ((row >> 1) & 3);
            glds16(A  + ((size_t)(bi + row) * D_SZ + k0 + g * 8), As + s * 8);
            glds16(Bt + ((size_t)(bj + row) * D_SZ + k0 + g * 8), Bs + s * 8);
        }
        __syncthreads();   // drains vmcnt (global_load_lds) before reads

        short8 af[4], bf[4];
        #pragma unroll
        for (int mt = 0; mt < 4; ++mt) {
            int r = wm * 64 + mt * 16 + l16;
            af[mt] = *(const short8*)(As + r * 32 + pfrag * 8);
        }
        #pragma unroll
        for (int nt = 0; nt < 4; ++nt) {
            int r = wn * 64 + nt * 16 + l16;
            bf[nt] = *(const short8*)(Bs + r * 32 + pfrag * 8);
        }
        #pragma unroll
        for (int mt = 0; mt < 4; ++mt)
            #pragma unroll
            for (int nt = 0; nt < 4; ++nt)
                acc[mt][nt] = __builtin_amdgcn_mfma_f32_16x16x32_bf16(
                    af[mt], bf[nt], acc[mt][nt], 0, 0, 0);
        __syncthreads();   // protect LDS before next stage overwrites
    }

    // Epilogue: logits -> -log_sigmoid(label*logit) = softplus(-z), reduce.
    // Fast path: softplus(-z) = max(-z,0) + log(1+exp(-|z|)) with hw
    // v_exp_f32/v_log_f32 (__expf/__logf). Abs err vs log1pf ~6e-8/term;
    // summed over 8192^2 terms and /B -> ~5e-4, threshold 0.2075.
    const float t    = fminf(__expf(tp[0]), 100.0f);
    const float bias = bp[0];
    float lsum = 0.0f;
    #pragma unroll
    for (int mt = 0; mt < 4; ++mt) {
        #pragma unroll
        for (int nt = 0; nt < 4; ++nt) {
            const int jj = bj + wn * 64 + nt * 16 + l16;           // C/D col = lane&15
            #pragma unroll
            for (int r = 0; r < 4; ++r) {
                const int ii = bi + wm * 64 + mt * 16 + quad * 4 + r; // C/D row
                float logit = fmaf(acc[mt][nt][r], t, bias);
                float z = (ii == jj) ? logit : -logit;
                float e = __expf(-fabsf(z));
                lsum += fmaxf(-z, 0.0f) + __logf(1.0f + e);
            }
        }
    }
    #pragma unroll
    for (int off = 32; off > 0; off >>= 1) lsum += __shfl_down(lsum, off, 64);

    __shared__ float red[4];
    if (lane == 0) red[wave] = lsum;
    __syncthreads();
    if (tid == 0)
        atomicAdd(out, (red[0] + red[1] + red[2] + red[3]) * (1.0f / (float)B_SZ));
}

extern "C" void kernel_launch(void* const* d_in, const int* in_sizes, int n_in,
                              void* d_out, int out_size, void* d_ws, size_t ws_size,
                              hipStream_t stream) {
    const float* img = (const float*)d_in[0];
    const float* txt = (const float*)d_in[1];
    const float* tp  = (const float*)d_in[2];
    const float* bp  = (const float*)d_in[3];
    float* out = (float*)d_out;

    unsigned short* imgN = (unsigned short*)d_ws;                 // 16 MB
    unsigned short* txtN = imgN + (size_t)B_SZ * D_SZ;            // 16 MB

    hipMemsetAsync(out, 0, sizeof(float), stream);                // graph-capturable
    norm_cast_kernel<<<2 * B_SZ, 256, 0, stream>>>(img, txt, imgN, txtN);
    dim3 grid(B_SZ / 128, B_SZ / 128);
    siglip_gemm_loss<<<grid, 256, 0, stream>>>(imgN, txtN, tp, bp, out);
}

// Round 3
// 203.275 us; speedup vs baseline: 1.8140x; 1.3653x over previous
//
#include <hip/hip_runtime.h>
#include <hip/hip_bf16.h>

#define B_SZ 8192
#define D_SZ 1024   // elements; == bytes in fp8

typedef __attribute__((ext_vector_type(4))) float floatx4;
typedef __attribute__((ext_vector_type(8))) int   int8v;
typedef __attribute__((ext_vector_type(4))) int   int4v;

__device__ __forceinline__ void glds16(const void* g, void* l) {
    __builtin_amdgcn_global_load_lds(
        (const __attribute__((address_space(1))) void*)g,
        (__attribute__((address_space(3))) void*)l, 16, 0, 0);
}

// One wave per row (rows 0..8191 = img, 8192..16383 = txt). 4 rows/block.
// Lane holds 4 strided float4 chunks (16 elems), butterfly-reduce sumsq,
// scale, pack to OCP e4m3 via hw cvt, store 4 B/lane (coalesced).
__global__ __launch_bounds__(256) void norm_cast_fp8(
    const float* __restrict__ img, const float* __restrict__ txt,
    unsigned char* __restrict__ imgQ, unsigned char* __restrict__ txtQ)
{
    const int lane = threadIdx.x & 63;
    int w = blockIdx.x * 4 + (threadIdx.x >> 6);
    const float* src; unsigned char* dst;
    if (w < B_SZ) { src = img + (size_t)w * D_SZ; dst = imgQ + (size_t)w * D_SZ; }
    else { w -= B_SZ; src = txt + (size_t)w * D_SZ; dst = txtQ + (size_t)w * D_SZ; }

    float4 v[4];
    float ss = 0.0f;
    #pragma unroll
    for (int i = 0; i < 4; ++i) {
        v[i] = ((const float4*)src)[lane + 64 * i];
        ss += v[i].x*v[i].x + v[i].y*v[i].y + v[i].z*v[i].z + v[i].w*v[i].w;
    }
    #pragma unroll
    for (int off = 1; off < 64; off <<= 1) ss += __shfl_xor(ss, off, 64);
    const float scale = 1.0f / fmaxf(sqrtf(ss), 1e-12f);

    #pragma unroll
    for (int i = 0; i < 4; ++i) {
        int packed = 0;
        packed = __builtin_amdgcn_cvt_pk_fp8_f32(v[i].x * scale, v[i].y * scale, packed, false);
        packed = __builtin_amdgcn_cvt_pk_fp8_f32(v[i].z * scale, v[i].w * scale, packed, true);
        ((int*)dst)[lane + 64 * i] = packed;
    }
}

// Fused MX-fp8 GEMM (A @ B^T, both K-contiguous) + SigLIP loss reduction.
// 128x128 tile / block, 4 waves in 2x2, each wave 64x64 via 4x4 grid of
// 16x16x128 scaled-MFMA (scales pinned to 1.0). BK=128 -> 8 K-iterations.
//
// LDS rows are 128 B (one full bank cycle): unswizzled fragment reads would
// be 16-way bank-conflicted. The 16 B granule at logical (row, g) is stored
// at physical p = g ^ (row&7); swizzle applied on the GLOBAL address side of
// global_load_lds so the LDS side stays slot-contiguous (wave-uniform base +
// lane*16 as the DMA requires). Fragment ds_read_b128s then alias 2-way (free).
__global__ __launch_bounds__(256) void siglip_gemm_loss_fp8(
    const unsigned char* __restrict__ A,   // imgQ [B,D] e4m3
    const unsigned char* __restrict__ Bt,  // txtQ [B,D] e4m3
    const float* __restrict__ tp, const float* __restrict__ bp,
    float* __restrict__ out)
{
    __shared__ __align__(16) unsigned char As[128 * 128];
    __shared__ __align__(16) unsigned char Bs[128 * 128];

    const int tid  = threadIdx.x;
    const int lane = tid & 63;
    const int wave = tid >> 6;
    const int wm = wave & 1, wn = wave >> 1;
    const int bi = blockIdx.x * 128;
    const int bj = blockIdx.y * 128;
    const int quad = lane >> 4;   // 0..3 -> K-chunk of 32 bytes
    const int l16  = lane & 15;
    const int sw   = l16 & 7;     // row-dependent swizzle term (row&7 == l16&7)

    floatx4 acc[4][4];
    #pragma unroll
    for (int i = 0; i < 4; ++i)
        #pragma unroll
        for (int j = 0; j < 4; ++j)
            acc[i][j] = (floatx4){0.f, 0.f, 0.f, 0.f};

    for (int k0 = 0; k0 < D_SZ; k0 += 128) {
        // stage 128x128 B tiles: 1024 granules of 16 B each per matrix.
        // slot s -> row = s>>3, phys p = s&7, global granule g = p^(row&7).
        #pragma unroll
        for (int it = 0; it < 4; ++it) {
            int s = tid + it * 256;
            int row = s >> 3, p = s & 7;
            int g = p ^ (row & 7);
            glds16(A  + ((size_t)(bi + row) * D_SZ + k0 + g * 16), As + s * 16);
            glds16(Bt + ((size_t)(bj + row) * D_SZ + k0 + g * 16), Bs + s * 16);
        }
        __syncthreads();   // drains vmcnt (global_load_lds) before reads

        int8v af[4], bf[4];
        #pragma unroll
        for (int mt = 0; mt < 4; ++mt) {
            int r = wm * 64 + mt * 16 + l16;
            int4v lo = *(const int4v*)(As + r * 128 + (((quad*2)    ) ^ sw) * 16);
            int4v hi = *(const int4v*)(As + r * 128 + (((quad*2) + 1) ^ sw) * 16);
            af[mt][0]=lo[0]; af[mt][1]=lo[1]; af[mt][2]=lo[2]; af[mt][3]=lo[3];
            af[mt][4]=hi[0]; af[mt][5]=hi[1]; af[mt][6]=hi[2]; af[mt][7]=hi[3];
        }
        #pragma unroll
        for (int nt = 0; nt < 4; ++nt) {
            int r = wn * 64 + nt * 16 + l16;
            int4v lo = *(const int4v*)(Bs + r * 128 + (((quad*2)    ) ^ sw) * 16);
            int4v hi = *(const int4v*)(Bs + r * 128 + (((quad*2) + 1) ^ sw) * 16);
            bf[nt][0]=lo[0]; bf[nt][1]=lo[1]; bf[nt][2]=lo[2]; bf[nt][3]=lo[3];
            bf[nt][4]=hi[0]; bf[nt][5]=hi[1]; bf[nt][6]=hi[2]; bf[nt][7]=hi[3];
        }
        #pragma unroll
        for (int mt = 0; mt < 4; ++mt)
            #pragma unroll
            for (int nt = 0; nt < 4; ++nt)
                acc[mt][nt] = __builtin_amdgcn_mfma_scale_f32_16x16x128_f8f6f4(
                    af[mt], bf[nt], acc[mt][nt],
                    0, 0,          // cbsz=fp8, blgp=fp8
                    0, 127,        // scale A: opsel 0, E8M0 127 = 1.0
                    0, 127);       // scale B
        __syncthreads();   // protect LDS before next stage overwrites
    }

    // Epilogue: logits -> softplus(-label*logit) with hw exp/log, reduce.
    const float t    = fminf(__expf(tp[0]), 100.0f);
    const float bias = bp[0];
    float lsum = 0.0f;
    #pragma unroll
    for (int mt = 0; mt < 4; ++mt) {
        #pragma unroll
        for (int nt = 0; nt < 4; ++nt) {
            const int jj = bj + wn * 64 + nt * 16 + l16;              // C/D col = lane&15
            #pragma unroll
            for (int r = 0; r < 4; ++r) {
                const int ii = bi + wm * 64 + mt * 16 + quad * 4 + r; // C/D row
                float logit = fmaf(acc[mt][nt][r], t, bias);
                float z = (ii == jj) ? logit : -logit;
                float e = __expf(-fabsf(z));
                lsum += fmaxf(-z, 0.0f) + __logf(1.0f + e);
            }
        }
    }
    #pragma unroll
    for (int off = 32; off > 0; off >>= 1) lsum += __shfl_down(lsum, off, 64);

    __shared__ float red[4];
    if (lane == 0) red[wave] = lsum;
    __syncthreads();
    if (tid == 0)
        atomicAdd(out, (red[0] + red[1] + red[2] + red[3]) * (1.0f / (float)B_SZ));
}

extern "C" void kernel_launch(void* const* d_in, const int* in_sizes, int n_in,
                              void* d_out, int out_size, void* d_ws, size_t ws_size,
                              hipStream_t stream) {
    const float* img = (const float*)d_in[0];
    const float* txt = (const float*)d_in[1];
    const float* tp  = (const float*)d_in[2];
    const float* bp  = (const float*)d_in[3];
    float* out = (float*)d_out;

    unsigned char* imgQ = (unsigned char*)d_ws;                   // 8 MB
    unsigned char* txtQ = imgQ + (size_t)B_SZ * D_SZ;             // 8 MB

    hipMemsetAsync(out, 0, sizeof(float), stream);                // graph-capturable
    norm_cast_fp8<<<(2 * B_SZ) / 4, 256, 0, stream>>>(img, txt, imgQ, txtQ);
    dim3 grid(B_SZ / 128, B_SZ / 128);
    siglip_gemm_loss_fp8<<<grid, 256, 0, stream>>>(imgQ, txtQ, tp, bp, out);
}

// Round 4
// 192.322 us; speedup vs baseline: 1.9173x; 1.0569x over previous
//
#include <hip/hip_runtime.h>
#include <hip/hip_bf16.h>

#define B_SZ 8192
#define D_SZ 1024   // elements; == bytes in fp8

typedef __attribute__((ext_vector_type(4))) float floatx4;
typedef __attribute__((ext_vector_type(8))) int   int8v;
typedef __attribute__((ext_vector_type(4))) int   int4v;

__device__ __forceinline__ void glds16(const void* g, void* l) {
    __builtin_amdgcn_global_load_lds(
        (const __attribute__((address_space(1))) void*)g,
        (__attribute__((address_space(3))) void*)l, 16, 0, 0);
}

// One wave per row (rows 0..8191 = img, 8192..16383 = txt). 4 rows/block.
__global__ __launch_bounds__(256) void norm_cast_fp8(
    const float* __restrict__ img, const float* __restrict__ txt,
    unsigned char* __restrict__ imgQ, unsigned char* __restrict__ txtQ)
{
    const int lane = threadIdx.x & 63;
    int w = blockIdx.x * 4 + (threadIdx.x >> 6);
    const float* src; unsigned char* dst;
    if (w < B_SZ) { src = img + (size_t)w * D_SZ; dst = imgQ + (size_t)w * D_SZ; }
    else { w -= B_SZ; src = txt + (size_t)w * D_SZ; dst = txtQ + (size_t)w * D_SZ; }

    float4 v[4];
    float ss = 0.0f;
    #pragma unroll
    for (int i = 0; i < 4; ++i) {
        v[i] = ((const float4*)src)[lane + 64 * i];
        ss += v[i].x*v[i].x + v[i].y*v[i].y + v[i].z*v[i].z + v[i].w*v[i].w;
    }
    #pragma unroll
    for (int off = 1; off < 64; off <<= 1) ss += __shfl_xor(ss, off, 64);
    const float scale = 1.0f / fmaxf(sqrtf(ss), 1e-12f);

    #pragma unroll
    for (int i = 0; i < 4; ++i) {
        int packed = 0;
        packed = __builtin_amdgcn_cvt_pk_fp8_f32(v[i].x * scale, v[i].y * scale, packed, false);
        packed = __builtin_amdgcn_cvt_pk_fp8_f32(v[i].z * scale, v[i].w * scale, packed, true);
        ((int*)dst)[lane + 64 * i] = packed;
    }
}

// Fused MX-fp8 GEMM (A @ B^T) + SigLIP loss. 128x128 tile, 4 waves 2x2,
// 16x16x128 scaled-MFMA (scales = 1.0), BK=128 -> 8 K-iters.
//
// LDS: each matrix tile stored as TWO arrays (lo = K-bytes 0..63, hi =
// 64..127) with 64 B rows — R2's empirically conflict-free geometry
// (consecutive rows interleave the two halves of the 128 B bank cycle).
// Within each array the 16 B granule at logical g (0..3) sits at physical
// p = g ^ ((row>>1)&3); the swizzle lives on the GLOBAL address side of
// global_load_lds so LDS slots stay contiguous (wave-uniform base + lane*16).
//
// K-loop is restructured for intra-block overlap: fragments are pulled into
// registers first, then the NEXT tile's DMA is issued, then MFMAs run while
// the DMA is in flight. barrier(A) at loop top drains each wave's own vmcnt
// (= DMA complete); barrier(B) after the ds_reads licenses the overwrite.
__global__ __launch_bounds__(256, 3) void siglip_gemm_loss_fp8(
    const unsigned char* __restrict__ A,   // imgQ [B,D] e4m3
    const unsigned char* __restrict__ Bt,  // txtQ [B,D] e4m3
    const float* __restrict__ tp, const float* __restrict__ bp,
    float* __restrict__ out)
{
    __shared__ __align__(16) unsigned char As[2][128 * 64]; // [0]=lo [1]=hi
    __shared__ __align__(16) unsigned char Bs[2][128 * 64];

    const int tid  = threadIdx.x;
    const int lane = tid & 63;
    const int wave = tid >> 6;
    const int wm = wave & 1, wn = wave >> 1;
    const int bi = blockIdx.x * 128;
    const int bj = blockIdx.y * 128;
    const int quad = lane >> 4;   // 0..3 -> 32-byte K-chunk
    const int l16  = lane & 15;

    floatx4 acc[4][4];
    #pragma unroll
    for (int i = 0; i < 4; ++i)
        #pragma unroll
        for (int j = 0; j < 4; ++j)
            acc[i][j] = (floatx4){0.f, 0.f, 0.f, 0.f};

    // staging: 512 slots per array; slot s -> row = s>>2, phys p = s&3,
    // global granule g = p ^ ((row>>1)&3); lo at k-byte g*16, hi at 64+g*16.
    auto stage = [&](int k0) {
        #pragma unroll
        for (int it = 0; it < 2; ++it) {
            int s = tid + it * 256;
            int row = s >> 2, p = s & 3;
            int g = p ^ ((row >> 1) & 3);
            const unsigned char* ga = A  + ((size_t)(bi + row) * D_SZ + k0 + g * 16);
            const unsigned char* gb = Bt + ((size_t)(bj + row) * D_SZ + k0 + g * 16);
            glds16(ga,      As[0] + s * 16);
            glds16(ga + 64, As[1] + s * 16);
            glds16(gb,      Bs[0] + s * 16);
            glds16(gb + 64, Bs[1] + s * 16);
        }
    };

    // fragment read geometry: quad -> array (quad>>1), within-array granule
    // pair q2,q2+1 (q2 = (quad&1)*2), physical pos XOR'd by (l16>>1)&3
    // (row base is a multiple of 16 so (row>>1)&3 == (l16>>1)&3).
    const int sw = (l16 >> 1) & 3;
    const int hsel = quad >> 1;
    const int q2 = (quad & 1) * 2;
    const int p0 = (q2    ) ^ sw;
    const int p1 = (q2 + 1) ^ sw;

    stage(0);

    for (int kk = 0; kk < D_SZ / 128; ++kk) {
        __syncthreads();   // (A) own-DMA vmcnt drained by barrier semantics

        int8v af[4], bf[4];
        #pragma unroll
        for (int mt = 0; mt < 4; ++mt) {
            int r = wm * 64 + mt * 16 + l16;
            int4v lo = *(const int4v*)(As[hsel] + r * 64 + p0 * 16);
            int4v hi = *(const int4v*)(As[hsel] + r * 64 + p1 * 16);
            af[mt][0]=lo[0]; af[mt][1]=lo[1]; af[mt][2]=lo[2]; af[mt][3]=lo[3];
            af[mt][4]=hi[0]; af[mt][5]=hi[1]; af[mt][6]=hi[2]; af[mt][7]=hi[3];
        }
        #pragma unroll
        for (int nt = 0; nt < 4; ++nt) {
            int r = wn * 64 + nt * 16 + l16;
            int4v lo = *(const int4v*)(Bs[hsel] + r * 64 + p0 * 16);
            int4v hi = *(const int4v*)(Bs[hsel] + r * 64 + p1 * 16);
            bf[nt][0]=lo[0]; bf[nt][1]=lo[1]; bf[nt][2]=lo[2]; bf[nt][3]=lo[3];
            bf[nt][4]=hi[0]; bf[nt][5]=hi[1]; bf[nt][6]=hi[2]; bf[nt][7]=hi[3];
        }

        __syncthreads();   // (B) all waves done reading LDS (lgkm only)

        if (kk + 1 < D_SZ / 128)
            stage((kk + 1) * 128);   // DMA flies during the MFMA phase below

        #pragma unroll
        for (int mt = 0; mt < 4; ++mt)
            #pragma unroll
            for (int nt = 0; nt < 4; ++nt)
                acc[mt][nt] = __builtin_amdgcn_mfma_scale_f32_16x16x128_f8f6f4(
                    af[mt], bf[nt], acc[mt][nt],
                    0, 0,          // cbsz=fp8, blgp=fp8
                    0, 127,        // scale A: E8M0 127 = 1.0
                    0, 127);       // scale B
    }

    // Epilogue: softplus(-label*logit) with hw exp/log, reduce.
    const float t    = fminf(__expf(tp[0]), 100.0f);
    const float bias = bp[0];
    float lsum = 0.0f;
    #pragma unroll
    for (int mt = 0; mt < 4; ++mt) {
        #pragma unroll
        for (int nt = 0; nt < 4; ++nt) {
            const int jj = bj + wn * 64 + nt * 16 + l16;              // C/D col
            #pragma unroll
            for (int r = 0; r < 4; ++r) {
                const int ii = bi + wm * 64 + mt * 16 + quad * 4 + r; // C/D row
                float logit = fmaf(acc[mt][nt][r], t, bias);
                float z = (ii == jj) ? logit : -logit;
                float e = __expf(-fabsf(z));
                lsum += fmaxf(-z, 0.0f) + __logf(1.0f + e);
            }
        }
    }
    #pragma unroll
    for (int off = 32; off > 0; off >>= 1) lsum += __shfl_down(lsum, off, 64);

    __shared__ float red[4];
    if (lane == 0) red[wave] = lsum;
    __syncthreads();
    if (tid == 0)
        atomicAdd(out, (red[0] + red[1] + red[2] + red[3]) * (1.0f / (float)B_SZ));
}

extern "C" void kernel_launch(void* const* d_in, const int* in_sizes, int n_in,
                              void* d_out, int out_size, void* d_ws, size_t ws_size,
                              hipStream_t stream) {
    const float* img = (const float*)d_in[0];
    const float* txt = (const float*)d_in[1];
    const float* tp  = (const float*)d_in[2];
    const float* bp  = (const float*)d_in[3];
    float* out = (float*)d_out;

    unsigned char* imgQ = (unsigned char*)d_ws;                   // 8 MB
    unsigned char* txtQ = imgQ + (size_t)B_SZ * D_SZ;             // 8 MB

    hipMemsetAsync(out, 0, sizeof(float), stream);                // graph-capturable
    norm_cast_fp8<<<(2 * B_SZ) / 4, 256, 0, stream>>>(img, txt, imgQ, txtQ);
    dim3 grid(B_SZ / 128, B_SZ / 128);
    siglip_gemm_loss_fp8<<<grid, 256, 0, stream>>>(imgQ, txtQ, tp, bp, out);
}